// Round 1
// baseline (990.880 us; speedup 1.0000x reference)
//
#include <hip/hip_runtime.h>
#include <math.h>

#define N_NODES 20000
#define N_EDGES 320000
#define E_TOT   (N_EDGES + N_NODES)
#define HID     128
#define HEADS   4
#define NEG_SLOPE 0.2f

// ---------------- CSR build ----------------
__global__ void k_init_deg(int* __restrict__ deg) {
  int i = blockIdx.x * blockDim.x + threadIdx.x;
  if (i < N_NODES) deg[i] = 1;  // self loop
}

__global__ void k_hist(const int* __restrict__ ei, int* __restrict__ deg) {
  int e = blockIdx.x * blockDim.x + threadIdx.x;
  if (e < N_EDGES) atomicAdd(&deg[ei[N_EDGES + e]], 1);
}

__global__ __launch_bounds__(1024) void k_scan(int* __restrict__ deg,
                                               int* __restrict__ row_ptr) {
  __shared__ int sums[1024];
  int t = threadIdx.x;
  const int CH = 20;
  int begin = t * CH;
  int end = begin + CH; if (end > N_NODES) end = N_NODES;
  int loc = 0;
  for (int i = begin; i < end; ++i) loc += deg[i];
  sums[t] = loc;
  __syncthreads();
  for (int off = 1; off < 1024; off <<= 1) {
    int v = (t >= off) ? sums[t - off] : 0;
    __syncthreads();
    sums[t] += v;
    __syncthreads();
  }
  int run = (t > 0) ? sums[t - 1] : 0;
  for (int i = begin; i < end; ++i) {
    int d = deg[i];
    row_ptr[i] = run;
    run += d;
    deg[i] = 0;      // becomes the scatter cursor
  }
  if (t == 1023) row_ptr[N_NODES] = sums[1023];
}

__global__ void k_scatter(const int* __restrict__ ei, const int* __restrict__ row_ptr,
                          int* __restrict__ cursor, int* __restrict__ edge_src) {
  int t = blockIdx.x * blockDim.x + threadIdx.x;
  if (t < N_EDGES) {
    int s = ei[t], d = ei[N_EDGES + t];
    int pos = row_ptr[d] + atomicAdd(&cursor[d], 1);
    edge_src[pos] = s;
  } else if (t < E_TOT) {
    int i = t - N_EDGES;
    int pos = row_ptr[i] + atomicAdd(&cursor[i], 1);
    edge_src[pos] = i;
  }
}

// ---------------- generic f32 tiled GEMM: C = act(A[:,c0:c0+K] @ B + bias) ----------------
// A row-major [M x lda], B row-major [K x N] (N % 64 == 0, K % 16 == 0)
__global__ __launch_bounds__(256) void k_gemm(
    const float* __restrict__ A, int lda, int c0,
    const float* __restrict__ B,
    const float* __restrict__ bias,
    float* __restrict__ C, int ldc,
    int M, int N, int K, int act) {
  __shared__ float As[16][65];
  __shared__ float Bs[16][64];
  int tid = threadIdx.x;
  int bm = blockIdx.x * 64, bn = blockIdx.y * 64;
  int tx = tid & 15, ty = tid >> 4;
  float acc[4][4] = {{0.f}};
  for (int k0 = 0; k0 < K; k0 += 16) {
    for (int r = 0; r < 4; ++r) {
      int m = (tid >> 4) + (r << 4);
      int gm = bm + m;
      float v = 0.f;
      if (gm < M) v = A[(size_t)gm * lda + c0 + k0 + (tid & 15)];
      As[tid & 15][m] = v;
    }
    for (int r = 0; r < 4; ++r) {
      int k = (tid >> 6) + (r << 2);
      Bs[k][tid & 63] = B[(size_t)(k0 + k) * N + bn + (tid & 63)];
    }
    __syncthreads();
    #pragma unroll
    for (int k = 0; k < 16; ++k) {
      float a[4], b[4];
      #pragma unroll
      for (int i = 0; i < 4; ++i) a[i] = As[k][ty + (i << 4)];
      #pragma unroll
      for (int j = 0; j < 4; ++j) b[j] = Bs[k][tx + (j << 4)];
      #pragma unroll
      for (int i = 0; i < 4; ++i)
        #pragma unroll
        for (int j = 0; j < 4; ++j) acc[i][j] += a[i] * b[j];
    }
    __syncthreads();
  }
  for (int i = 0; i < 4; ++i) {
    int gm = bm + ty + (i << 4);
    if (gm >= M) continue;
    for (int j = 0; j < 4; ++j) {
      int gn = bn + tx + (j << 4);
      float v = acc[i][j] + (bias ? bias[gn] : 0.f);
      if (act == 1) v = fmaxf(v, 0.f);
      C[(size_t)gm * ldc + gn] = v;
    }
  }
}

// ---------------- attention logits: als/ald[n][h] = <xh[n,h,:], a_src/a_dst[h,:]> ----------------
__global__ __launch_bounds__(256) void k_attn(const float* __restrict__ xh,
                                              const float* __restrict__ a_src,
                                              const float* __restrict__ a_dst,
                                              float* __restrict__ als,
                                              float* __restrict__ ald) {
  int node = blockIdx.x;
  int w = threadIdx.x >> 6;       // head
  int lane = threadIdx.x & 63;
  const float* xp = xh + (size_t)node * 512 + w * 128;
  float x0 = xp[lane], x1 = xp[64 + lane];
  float ps = x0 * a_src[w * 128 + lane] + x1 * a_src[w * 128 + 64 + lane];
  float pd = x0 * a_dst[w * 128 + lane] + x1 * a_dst[w * 128 + 64 + lane];
  for (int off = 32; off > 0; off >>= 1) {
    ps += __shfl_down(ps, off);
    pd += __shfl_down(pd, off);
  }
  if (lane == 0) {
    als[node * 4 + w] = ps;
    ald[node * 4 + w] = pd;
  }
}

__device__ __forceinline__ float lrelu(float x) { return x > 0.f ? x : NEG_SLOPE * x; }

// ---------------- fused GAT aggregation (per-dst CSR): softmax + message sum + mean + bias + elu + residual ----------------
__global__ __launch_bounds__(128) void k_agg(const float* __restrict__ xh,
                                             const float* __restrict__ als,
                                             const float* __restrict__ ald,
                                             const int* __restrict__ row_ptr,
                                             const int* __restrict__ edge_src,
                                             const float* __restrict__ bias,
                                             float* __restrict__ h) {
  int node = blockIdx.x;
  int tid = threadIdx.x;  // 0..127
  __shared__ float red[4 * 128];
  int begin = row_ptr[node], end = row_ptr[node + 1];
  float4 ad4 = *(const float4*)(ald + (size_t)node * 4);

  // phase A: max per head
  float lm0 = -1e30f, lm1 = -1e30f, lm2 = -1e30f, lm3 = -1e30f;
  for (int idx = begin + tid; idx < end; idx += 128) {
    int s = edge_src[idx];
    float4 a4 = *(const float4*)(als + (size_t)s * 4);
    lm0 = fmaxf(lm0, lrelu(a4.x + ad4.x));
    lm1 = fmaxf(lm1, lrelu(a4.y + ad4.y));
    lm2 = fmaxf(lm2, lrelu(a4.z + ad4.z));
    lm3 = fmaxf(lm3, lrelu(a4.w + ad4.w));
  }
  red[tid] = lm0; red[128 + tid] = lm1; red[256 + tid] = lm2; red[384 + tid] = lm3;
  __syncthreads();
  for (int off = 64; off > 0; off >>= 1) {
    if (tid < off) {
      red[tid]       = fmaxf(red[tid],       red[tid + off]);
      red[128 + tid] = fmaxf(red[128 + tid], red[128 + tid + off]);
      red[256 + tid] = fmaxf(red[256 + tid], red[256 + tid + off]);
      red[384 + tid] = fmaxf(red[384 + tid], red[384 + tid + off]);
    }
    __syncthreads();
  }
  float m0 = red[0], m1 = red[128], m2 = red[256], m3 = red[384];
  __syncthreads();

  // phase B: sum of exp
  float ls0 = 0.f, ls1 = 0.f, ls2 = 0.f, ls3 = 0.f;
  for (int idx = begin + tid; idx < end; idx += 128) {
    int s = edge_src[idx];
    float4 a4 = *(const float4*)(als + (size_t)s * 4);
    ls0 += expf(lrelu(a4.x + ad4.x) - m0);
    ls1 += expf(lrelu(a4.y + ad4.y) - m1);
    ls2 += expf(lrelu(a4.z + ad4.z) - m2);
    ls3 += expf(lrelu(a4.w + ad4.w) - m3);
  }
  red[tid] = ls0; red[128 + tid] = ls1; red[256 + tid] = ls2; red[384 + tid] = ls3;
  __syncthreads();
  for (int off = 64; off > 0; off >>= 1) {
    if (tid < off) {
      red[tid]       += red[tid + off];
      red[128 + tid] += red[128 + tid + off];
      red[256 + tid] += red[256 + tid + off];
      red[384 + tid] += red[384 + tid + off];
    }
    __syncthreads();
  }
  float inv0 = 1.f / (red[0]   + 1e-16f);
  float inv1 = 1.f / (red[128] + 1e-16f);
  float inv2 = 1.f / (red[256] + 1e-16f);
  float inv3 = 1.f / (red[384] + 1e-16f);

  // phase C: weighted message accumulation (all threads walk all edges together)
  float acc0 = 0.f, acc1 = 0.f, acc2 = 0.f, acc3 = 0.f;
  for (int idx = begin; idx < end; ++idx) {
    int s = edge_src[idx];
    float4 a4 = *(const float4*)(als + (size_t)s * 4);
    float al0 = expf(lrelu(a4.x + ad4.x) - m0) * inv0;
    float al1 = expf(lrelu(a4.y + ad4.y) - m1) * inv1;
    float al2 = expf(lrelu(a4.z + ad4.z) - m2) * inv2;
    float al3 = expf(lrelu(a4.w + ad4.w) - m3) * inv3;
    const float* xr = xh + (size_t)s * 512;
    acc0 += al0 * xr[tid];
    acc1 += al1 * xr[128 + tid];
    acc2 += al2 * xr[256 + tid];
    acc3 += al3 * xr[384 + tid];
  }
  float val = 0.25f * (acc0 + acc1 + acc2 + acc3) + bias[tid];
  val = val > 0.f ? val : expf(val) - 1.f;  // elu
  size_t o = (size_t)node * 128 + tid;
  h[o] = val + h[o];
}

// ---------------- modal gating + final embedding ----------------
__global__ __launch_bounds__(128) void k_modal(const float* __restrict__ hv,
                                               const float* __restrict__ ht,
                                               const float* __restrict__ mw,
                                               const float* __restrict__ mb,
                                               float* __restrict__ out) {
  int node = blockIdx.x, t = threadIdx.x;
  __shared__ float red[128];
  float a = hv[(size_t)node * 128 + t];
  float b = ht[(size_t)node * 128 + t];
  red[t] = a * mw[t] + b * mw[128 + t];
  __syncthreads();
  for (int off = 64; off > 0; off >>= 1) {
    if (t < off) red[t] += red[t + off];
    __syncthreads();
  }
  float beta = 1.f / (1.f + expf(-(red[0] + mb[0])));
  out[(size_t)node * 128 + t] = beta * a + (1.f - beta) * b;
}

extern "C" void kernel_launch(void* const* d_in, const int* in_sizes, int n_in,
                              void* d_out, int out_size, void* d_ws, size_t ws_size,
                              hipStream_t stream) {
  const float* x    = (const float*)d_in[0];
  const int*   ei   = (const int*)d_in[1];
  const float* vpw  = (const float*)d_in[2];
  const float* vpb  = (const float*)d_in[3];
  const float* tpw  = (const float*)d_in[4];
  const float* tpb  = (const float*)d_in[5];
  const float* vgw  = (const float*)d_in[6];
  const float* vgas = (const float*)d_in[7];
  const float* vgad = (const float*)d_in[8];
  const float* vgb  = (const float*)d_in[9];
  const float* tgw  = (const float*)d_in[10];
  const float* tgas = (const float*)d_in[11];
  const float* tgad = (const float*)d_in[12];
  const float* tgb  = (const float*)d_in[13];
  const float* mw   = (const float*)d_in[14];
  const float* mb   = (const float*)d_in[15];
  const float* vhw  = (const float*)d_in[16];
  const float* vhb  = (const float*)d_in[17];
  const float* thw  = (const float*)d_in[18];
  const float* thb  = (const float*)d_in[19];
  float* out = (float*)d_out;

  char* ws = (char*)d_ws;
  float* h_v      = (float*)(ws);               // 10,240,000 B
  float* h_t      = (float*)(ws + 10240000);    // 10,240,000 B
  float* xh       = (float*)(ws + 20480000);    // 40,960,000 B
  float* als      = (float*)(ws + 61440000);    //    320,000 B
  float* ald      = (float*)(ws + 61760000);    //    320,000 B
  int*   row_ptr  = (int*)  (ws + 62080000);    //     80,016 B (20001 ints)
  int*   deg      = (int*)  (ws + 62160016);    //     80,000 B (also cursor)
  int*   edge_src = (int*)  (ws + 62240016);    //  1,360,000 B

  // CSR build (includes self loops)
  k_init_deg<<<(N_NODES + 255) / 256, 256, 0, stream>>>(deg);
  k_hist<<<(N_EDGES + 255) / 256, 256, 0, stream>>>(ei, deg);
  k_scan<<<1, 1024, 0, stream>>>(deg, row_ptr);
  k_scatter<<<(E_TOT + 255) / 256, 256, 0, stream>>>(ei, row_ptr, deg, edge_src);

  // input projections
  dim3 gp((N_NODES + 63) / 64, HID / 64);
  k_gemm<<<gp, 256, 0, stream>>>(x, 1152, 0,   vpw, vpb, h_v, HID, N_NODES, HID, 768, 1);
  k_gemm<<<gp, 256, 0, stream>>>(x, 1152, 768, tpw, tpb, h_t, HID, N_NODES, HID, 384, 1);

  // GAT layers
  dim3 gx((N_NODES + 63) / 64, 512 / 64);
  for (int L = 0; L < 2; ++L) {
    k_gemm<<<gx, 256, 0, stream>>>(h_v, HID, 0, vgw + (size_t)L * HID * 512, nullptr,
                                   xh, 512, N_NODES, 512, HID, 0);
    k_attn<<<N_NODES, 256, 0, stream>>>(xh, vgas + L * 512, vgad + L * 512, als, ald);
    k_agg<<<N_NODES, 128, 0, stream>>>(xh, als, ald, row_ptr, edge_src, vgb + L * HID, h_v);

    k_gemm<<<gx, 256, 0, stream>>>(h_t, HID, 0, tgw + (size_t)L * HID * 512, nullptr,
                                   xh, 512, N_NODES, 512, HID, 0);
    k_attn<<<N_NODES, 256, 0, stream>>>(xh, tgas + L * 512, tgad + L * 512, als, ald);
    k_agg<<<N_NODES, 128, 0, stream>>>(xh, als, ald, row_ptr, edge_src, tgb + L * HID, h_t);
  }

  // epilogue
  k_modal<<<N_NODES, 128, 0, stream>>>(h_v, h_t, mw, mb, out);
  k_gemm<<<gp, 256, 0, stream>>>(h_v, HID, 0, vhw, vhb, out + 2560000, HID, N_NODES, HID, HID, 1);
  k_gemm<<<gp, 256, 0, stream>>>(h_t, HID, 0, thw, thb, out + 5120000, HID, N_NODES, HID, HID, 1);
}

// Round 2
// 759.896 us; speedup vs baseline: 1.3040x; 1.3040x over previous
//
#include <hip/hip_runtime.h>
#include <math.h>

#define N_NODES 20000
#define N_EDGES 320000
#define E_TOT   (N_EDGES + N_NODES)
#define HID     128
#define NEG_SLOPE 0.2f

typedef __attribute__((ext_vector_type(8))) short short8;
typedef __attribute__((ext_vector_type(4))) float f32x4;

__device__ __forceinline__ unsigned short f2b(float f) {
  unsigned u = __builtin_bit_cast(unsigned, f);
  return (unsigned short)((u + 0x7fffu + ((u >> 16) & 1u)) >> 16);
}
__device__ __forceinline__ float b2f(unsigned short h) {
  unsigned u = ((unsigned)h) << 16;
  return __builtin_bit_cast(float, u);
}
__device__ __forceinline__ float lrelu(float x) { return x > 0.f ? x : NEG_SLOPE * x; }

// ---------------- CSR build ----------------
__global__ void k_init_deg(int* __restrict__ deg) {
  int i = blockIdx.x * blockDim.x + threadIdx.x;
  if (i < N_NODES) deg[i] = 1;  // self loop
}

__global__ void k_hist(const int* __restrict__ ei, int* __restrict__ deg) {
  int e = blockIdx.x * blockDim.x + threadIdx.x;
  if (e < N_EDGES) atomicAdd(&deg[ei[N_EDGES + e]], 1);
}

__global__ __launch_bounds__(1024) void k_scan(int* __restrict__ deg,
                                               int* __restrict__ row_ptr) {
  __shared__ int sums[1024];
  int t = threadIdx.x;
  const int CH = 20;
  int begin = t * CH;
  int end = begin + CH; if (end > N_NODES) end = N_NODES;
  int loc = 0;
  for (int i = begin; i < end; ++i) loc += deg[i];
  sums[t] = loc;
  __syncthreads();
  for (int off = 1; off < 1024; off <<= 1) {
    int v = (t >= off) ? sums[t - off] : 0;
    __syncthreads();
    sums[t] += v;
    __syncthreads();
  }
  int run = (t > 0) ? sums[t - 1] : 0;
  for (int i = begin; i < end; ++i) {
    int d = deg[i];
    row_ptr[i] = run;
    run += d;
    deg[i] = 0;      // becomes the scatter cursor
  }
  if (t == 1023) row_ptr[N_NODES] = sums[1023];
}

__global__ void k_scatter(const int* __restrict__ ei, const int* __restrict__ row_ptr,
                          int* __restrict__ cursor, int* __restrict__ edge_src) {
  int t = blockIdx.x * blockDim.x + threadIdx.x;
  if (t < N_EDGES) {
    int s = ei[t], d = ei[N_EDGES + t];
    int pos = row_ptr[d] + atomicAdd(&cursor[d], 1);
    edge_src[pos] = s;
  } else if (t < E_TOT) {
    int i = t - N_EDGES;
    int pos = row_ptr[i] + atomicAdd(&cursor[i], 1);
    edge_src[pos] = i;
  }
}

// ---------------- weight prep: W [K][N] f32 -> Bt [N][K] bf16 ----------------
__global__ void k_wt(const float* __restrict__ W, unsigned short* __restrict__ Bt,
                     int K, int N) {
  int idx = blockIdx.x * blockDim.x + threadIdx.x;
  if (idx < N * K) {
    int n = idx / K, k = idx - n * K;
    Bt[idx] = f2b(W[(size_t)k * N + n]);
  }
}

// ---------------- bf16 MFMA GEMM: C = act(A_f32[:, c0:c0+K] @ Bt^T + bias) ----------------
// A row-major f32 [M x lda]; Bt bf16 [N][K] (weights pre-transposed).
// Block tile 128x128, 4 waves (2x2), wave tile 64x64 = 4x4 frags of 16x16.
// LDS tiles [128 rows][64 k] bf16 with 16B-chunk XOR swizzle (chunk ^= row&7).
__global__ __launch_bounds__(256) void k_mfma(
    const float* __restrict__ A, int lda, int c0,
    const unsigned short* __restrict__ Bt,
    const float* __restrict__ bias,
    float* __restrict__ Cf, unsigned short* __restrict__ Cb, int ldc,
    int M, int K, int relu) {
  __shared__ unsigned short As[128 * 64];
  __shared__ unsigned short Bs[128 * 64];
  int t = threadIdx.x;
  int m0 = blockIdx.x * 128, n0 = blockIdx.y * 128;
  int w = t >> 6, l = t & 63;
  int wm = (w >> 1) * 64, wn = (w & 1) * 64;
  int lr = l & 15, lhi = l >> 4;
  int r = t >> 1, half = t & 1;

  f32x4 acc[4][4];
  #pragma unroll
  for (int i = 0; i < 4; ++i)
    #pragma unroll
    for (int j = 0; j < 4; ++j)
      acc[i][j] = (f32x4){0.f, 0.f, 0.f, 0.f};

  for (int k0 = 0; k0 < K; k0 += 64) {
    // stage A (f32 -> bf16 in-flight): thread handles row r, k-halves of 32
    {
      int gm = m0 + r;
      const float* ap = A + (size_t)gm * lda + c0 + k0 + half * 32;
      #pragma unroll
      for (int j = 0; j < 4; ++j) {
        float4 v0, v1;
        if (gm < M) {
          v0 = ((const float4*)ap)[2 * j];
          v1 = ((const float4*)ap)[2 * j + 1];
        } else {
          v0 = make_float4(0.f, 0.f, 0.f, 0.f); v1 = v0;
        }
        uint4 wv;
        wv.x = (unsigned)f2b(v0.x) | ((unsigned)f2b(v0.y) << 16);
        wv.y = (unsigned)f2b(v0.z) | ((unsigned)f2b(v0.w) << 16);
        wv.z = (unsigned)f2b(v1.x) | ((unsigned)f2b(v1.y) << 16);
        wv.w = (unsigned)f2b(v1.z) | ((unsigned)f2b(v1.w) << 16);
        int cb = half * 4 + j;
        *(uint4*)&As[r * 64 + ((cb ^ (r & 7)) << 3)] = wv;
      }
      // stage B (already bf16)
      const unsigned short* bp = Bt + (size_t)(n0 + r) * K + k0 + half * 32;
      #pragma unroll
      for (int j = 0; j < 4; ++j) {
        uint4 wv = ((const uint4*)bp)[j];
        int cb = half * 4 + j;
        *(uint4*)&Bs[r * 64 + ((cb ^ (r & 7)) << 3)] = wv;
      }
    }
    __syncthreads();
    #pragma unroll
    for (int kk = 0; kk < 2; ++kk) {
      short8 af[4], bfr[4];
      #pragma unroll
      for (int i = 0; i < 4; ++i) {
        int row = wm + i * 16 + lr;
        int cb = lhi + kk * 4;
        af[i] = *(const short8*)&As[row * 64 + ((cb ^ (row & 7)) << 3)];
      }
      #pragma unroll
      for (int j = 0; j < 4; ++j) {
        int nn = wn + j * 16 + lr;
        int cb = lhi + kk * 4;
        bfr[j] = *(const short8*)&Bs[nn * 64 + ((cb ^ (nn & 7)) << 3)];
      }
      #pragma unroll
      for (int i = 0; i < 4; ++i)
        #pragma unroll
        for (int j = 0; j < 4; ++j)
          acc[i][j] = __builtin_amdgcn_mfma_f32_16x16x32_bf16(af[i], bfr[j], acc[i][j], 0, 0, 0);
    }
    __syncthreads();
  }

  // epilogue: C/D layout col=lane&15, row=(lane>>4)*4+rr  [m89-verified]
  #pragma unroll
  for (int i = 0; i < 4; ++i) {
    int rowb = m0 + wm + i * 16 + lhi * 4;
    #pragma unroll
    for (int j = 0; j < 4; ++j) {
      int col = n0 + wn + j * 16 + lr;
      float bsv = bias ? bias[col] : 0.f;
      #pragma unroll
      for (int rr = 0; rr < 4; ++rr) {
        int gr = rowb + rr;
        if (gr < M) {
          float v = acc[i][j][rr] + bsv;
          if (relu) v = fmaxf(v, 0.f);
          if (Cf) Cf[(size_t)gr * ldc + col] = v;
          if (Cb) Cb[(size_t)gr * ldc + col] = f2b(v);
        }
      }
    }
  }
}

// ---------------- attention logits from bf16 xh ----------------
__global__ __launch_bounds__(256) void k_attn(const unsigned short* __restrict__ xh,
                                              const float* __restrict__ a_src,
                                              const float* __restrict__ a_dst,
                                              float* __restrict__ als,
                                              float* __restrict__ ald) {
  int node = blockIdx.x;
  int w = threadIdx.x >> 6;       // head
  int lane = threadIdx.x & 63;
  const unsigned short* xp = xh + (size_t)node * 512 + w * 128;
  float x0 = b2f(xp[lane]), x1 = b2f(xp[64 + lane]);
  float ps = x0 * a_src[w * 128 + lane] + x1 * a_src[w * 128 + 64 + lane];
  float pd = x0 * a_dst[w * 128 + lane] + x1 * a_dst[w * 128 + 64 + lane];
  for (int off = 32; off > 0; off >>= 1) {
    ps += __shfl_down(ps, off);
    pd += __shfl_down(pd, off);
  }
  if (lane == 0) {
    als[node * 4 + w] = ps;
    ald[node * 4 + w] = pd;
  }
}

// ---------------- fused GAT aggregation ----------------
__global__ __launch_bounds__(128) void k_agg(const unsigned short* __restrict__ xh,
                                             const float* __restrict__ als,
                                             const float* __restrict__ ald,
                                             const int* __restrict__ row_ptr,
                                             const int* __restrict__ edge_src,
                                             const float* __restrict__ bias,
                                             float* __restrict__ h) {
  int node = blockIdx.x;
  int tid = threadIdx.x;  // 0..127
  __shared__ float red[4 * 128];
  int begin = row_ptr[node], end = row_ptr[node + 1];
  float4 ad4 = *(const float4*)(ald + (size_t)node * 4);

  // phase A: max per head
  float lm0 = -1e30f, lm1 = -1e30f, lm2 = -1e30f, lm3 = -1e30f;
  for (int idx = begin + tid; idx < end; idx += 128) {
    int s = edge_src[idx];
    float4 a4 = *(const float4*)(als + (size_t)s * 4);
    lm0 = fmaxf(lm0, lrelu(a4.x + ad4.x));
    lm1 = fmaxf(lm1, lrelu(a4.y + ad4.y));
    lm2 = fmaxf(lm2, lrelu(a4.z + ad4.z));
    lm3 = fmaxf(lm3, lrelu(a4.w + ad4.w));
  }
  red[tid] = lm0; red[128 + tid] = lm1; red[256 + tid] = lm2; red[384 + tid] = lm3;
  __syncthreads();
  for (int off = 64; off > 0; off >>= 1) {
    if (tid < off) {
      red[tid]       = fmaxf(red[tid],       red[tid + off]);
      red[128 + tid] = fmaxf(red[128 + tid], red[128 + tid + off]);
      red[256 + tid] = fmaxf(red[256 + tid], red[256 + tid + off]);
      red[384 + tid] = fmaxf(red[384 + tid], red[384 + tid + off]);
    }
    __syncthreads();
  }
  float m0 = red[0], m1 = red[128], m2 = red[256], m3 = red[384];
  __syncthreads();

  // phase B: sum of exp
  float ls0 = 0.f, ls1 = 0.f, ls2 = 0.f, ls3 = 0.f;
  for (int idx = begin + tid; idx < end; idx += 128) {
    int s = edge_src[idx];
    float4 a4 = *(const float4*)(als + (size_t)s * 4);
    ls0 += expf(lrelu(a4.x + ad4.x) - m0);
    ls1 += expf(lrelu(a4.y + ad4.y) - m1);
    ls2 += expf(lrelu(a4.z + ad4.z) - m2);
    ls3 += expf(lrelu(a4.w + ad4.w) - m3);
  }
  red[tid] = ls0; red[128 + tid] = ls1; red[256 + tid] = ls2; red[384 + tid] = ls3;
  __syncthreads();
  for (int off = 64; off > 0; off >>= 1) {
    if (tid < off) {
      red[tid]       += red[tid + off];
      red[128 + tid] += red[128 + tid + off];
      red[256 + tid] += red[256 + tid + off];
      red[384 + tid] += red[384 + tid + off];
    }
    __syncthreads();
  }
  float inv0 = 1.f / (red[0]   + 1e-16f);
  float inv1 = 1.f / (red[128] + 1e-16f);
  float inv2 = 1.f / (red[256] + 1e-16f);
  float inv3 = 1.f / (red[384] + 1e-16f);

  // phase C: weighted message accumulation (bf16 gather)
  float acc0 = 0.f, acc1 = 0.f, acc2 = 0.f, acc3 = 0.f;
  for (int idx = begin; idx < end; ++idx) {
    int s = edge_src[idx];
    float4 a4 = *(const float4*)(als + (size_t)s * 4);
    float al0 = expf(lrelu(a4.x + ad4.x) - m0) * inv0;
    float al1 = expf(lrelu(a4.y + ad4.y) - m1) * inv1;
    float al2 = expf(lrelu(a4.z + ad4.z) - m2) * inv2;
    float al3 = expf(lrelu(a4.w + ad4.w) - m3) * inv3;
    const unsigned short* xr = xh + (size_t)s * 512;
    acc0 += al0 * b2f(xr[tid]);
    acc1 += al1 * b2f(xr[128 + tid]);
    acc2 += al2 * b2f(xr[256 + tid]);
    acc3 += al3 * b2f(xr[384 + tid]);
  }
  float val = 0.25f * (acc0 + acc1 + acc2 + acc3) + bias[tid];
  val = val > 0.f ? val : expf(val) - 1.f;  // elu
  size_t o = (size_t)node * 128 + tid;
  h[o] = val + h[o];
}

// ---------------- modal gating + final embedding ----------------
__global__ __launch_bounds__(128) void k_modal(const float* __restrict__ hv,
                                               const float* __restrict__ ht,
                                               const float* __restrict__ mw,
                                               const float* __restrict__ mb,
                                               float* __restrict__ out) {
  int node = blockIdx.x, t = threadIdx.x;
  __shared__ float red[128];
  float a = hv[(size_t)node * 128 + t];
  float b = ht[(size_t)node * 128 + t];
  red[t] = a * mw[t] + b * mw[128 + t];
  __syncthreads();
  for (int off = 64; off > 0; off >>= 1) {
    if (t < off) red[t] += red[t + off];
    __syncthreads();
  }
  float beta = 1.f / (1.f + expf(-(red[0] + mb[0])));
  out[(size_t)node * 128 + t] = beta * a + (1.f - beta) * b;
}

extern "C" void kernel_launch(void* const* d_in, const int* in_sizes, int n_in,
                              void* d_out, int out_size, void* d_ws, size_t ws_size,
                              hipStream_t stream) {
  const float* x    = (const float*)d_in[0];
  const int*   ei   = (const int*)d_in[1];
  const float* vpw  = (const float*)d_in[2];
  const float* vpb  = (const float*)d_in[3];
  const float* tpw  = (const float*)d_in[4];
  const float* tpb  = (const float*)d_in[5];
  const float* vgw  = (const float*)d_in[6];
  const float* vgas = (const float*)d_in[7];
  const float* vgad = (const float*)d_in[8];
  const float* vgb  = (const float*)d_in[9];
  const float* tgw  = (const float*)d_in[10];
  const float* tgas = (const float*)d_in[11];
  const float* tgad = (const float*)d_in[12];
  const float* tgb  = (const float*)d_in[13];
  const float* mw   = (const float*)d_in[14];
  const float* mb   = (const float*)d_in[15];
  const float* vhw  = (const float*)d_in[16];
  const float* vhb  = (const float*)d_in[17];
  const float* thw  = (const float*)d_in[18];
  const float* thb  = (const float*)d_in[19];
  float* out = (float*)d_out;

  char* ws = (char*)d_ws;
  float*          h_v      = (float*)(ws);                         // 10,240,000 B
  float*          h_t      = (float*)(ws + 10240000);              // 10,240,000 B
  unsigned short* xhb      = (unsigned short*)(ws + 20480000);     // 20,480,000 B
  float*          als      = (float*)(ws + 40960000);              //    320,000 B
  float*          ald      = (float*)(ws + 41280000);              //    320,000 B
  int*            row_ptr  = (int*)  (ws + 41600000);              //     80,016 B
  int*            deg      = (int*)  (ws + 41680016);              //     80,000 B
  int*            edge_src = (int*)  (ws + 41760016);              //  1,360,000 B
  unsigned short* bt       = (unsigned short*)(ws + 43120016);     //    884,736 B

  unsigned short* bt_vp = bt;            // [128][768]
  unsigned short* bt_tp = bt + 98304;    // [128][384]
  unsigned short* bt_vg = bt + 147456;   // 2 x [512][128]
  unsigned short* bt_tg = bt + 278528;   // 2 x [512][128]
  unsigned short* bt_vh = bt + 409600;   // [128][128]
  unsigned short* bt_th = bt + 425984;   // [128][128]

  // weight prep
  k_wt<<<(98304 + 255) / 256, 256, 0, stream>>>(vpw, bt_vp, 768, 128);
  k_wt<<<(49152 + 255) / 256, 256, 0, stream>>>(tpw, bt_tp, 384, 128);
  for (int L = 0; L < 2; ++L) {
    k_wt<<<(65536 + 255) / 256, 256, 0, stream>>>(vgw + (size_t)L * 65536, bt_vg + (size_t)L * 65536, 128, 512);
    k_wt<<<(65536 + 255) / 256, 256, 0, stream>>>(tgw + (size_t)L * 65536, bt_tg + (size_t)L * 65536, 128, 512);
  }
  k_wt<<<(16384 + 255) / 256, 256, 0, stream>>>(vhw, bt_vh, 128, 128);
  k_wt<<<(16384 + 255) / 256, 256, 0, stream>>>(thw, bt_th, 128, 128);

  // CSR build (includes self loops)
  k_init_deg<<<(N_NODES + 255) / 256, 256, 0, stream>>>(deg);
  k_hist<<<(N_EDGES + 255) / 256, 256, 0, stream>>>(ei, deg);
  k_scan<<<1, 1024, 0, stream>>>(deg, row_ptr);
  k_scatter<<<(E_TOT + 255) / 256, 256, 0, stream>>>(ei, row_ptr, deg, edge_src);

  // input projections (ReLU, f32 out)
  dim3 gp(157, 1);
  k_mfma<<<gp, 256, 0, stream>>>(x, 1152, 0,   bt_vp, vpb, h_v, nullptr, HID, N_NODES, 768, 1);
  k_mfma<<<gp, 256, 0, stream>>>(x, 1152, 768, bt_tp, tpb, h_t, nullptr, HID, N_NODES, 384, 1);

  // GAT layers
  dim3 gx(157, 4);
  for (int L = 0; L < 2; ++L) {
    k_mfma<<<gx, 256, 0, stream>>>(h_v, HID, 0, bt_vg + (size_t)L * 65536, nullptr,
                                   nullptr, xhb, 512, N_NODES, HID, 0);
    k_attn<<<N_NODES, 256, 0, stream>>>(xhb, vgas + L * 512, vgad + L * 512, als, ald);
    k_agg<<<N_NODES, 128, 0, stream>>>(xhb, als, ald, row_ptr, edge_src, vgb + L * HID, h_v);

    k_mfma<<<gx, 256, 0, stream>>>(h_t, HID, 0, bt_tg + (size_t)L * 65536, nullptr,
                                   nullptr, xhb, 512, N_NODES, HID, 0);
    k_attn<<<N_NODES, 256, 0, stream>>>(xhb, tgas + L * 512, tgad + L * 512, als, ald);
    k_agg<<<N_NODES, 128, 0, stream>>>(xhb, als, ald, row_ptr, edge_src, tgb + L * HID, h_t);
  }

  // epilogue
  k_modal<<<N_NODES, 128, 0, stream>>>(h_v, h_t, mw, mb, out);
  k_mfma<<<gp, 256, 0, stream>>>(h_v, HID, 0, bt_vh, vhb, out + 2560000, nullptr, HID, N_NODES, HID, 1);
  k_mfma<<<gp, 256, 0, stream>>>(h_t, HID, 0, bt_th, thb, out + 5120000, nullptr, HID, N_NODES, HID, 1);
}

// Round 3
// 550.154 us; speedup vs baseline: 1.8011x; 1.3812x over previous
//
#include <hip/hip_runtime.h>
#include <math.h>

#define N_NODES 20000
#define N_EDGES 320000
#define E_TOT   (N_EDGES + N_NODES)
#define HID     128
#define NEG_SLOPE 0.2f

typedef __attribute__((ext_vector_type(8))) short short8;
typedef __attribute__((ext_vector_type(4))) float f32x4;

__device__ __forceinline__ unsigned short f2b(float f) {
  unsigned u = __builtin_bit_cast(unsigned, f);
  return (unsigned short)((u + 0x7fffu + ((u >> 16) & 1u)) >> 16);
}
__device__ __forceinline__ float b2f(unsigned short h) {
  unsigned u = ((unsigned)h) << 16;
  return __builtin_bit_cast(float, u);
}
__device__ __forceinline__ float lrelu(float x) { return x > 0.f ? x : NEG_SLOPE * x; }

// ---------------- CSR build ----------------
__global__ void k_init_deg(int* __restrict__ deg) {
  int i = blockIdx.x * blockDim.x + threadIdx.x;
  if (i < N_NODES) deg[i] = 1;  // self loop
}

__global__ void k_hist(const int* __restrict__ ei, int* __restrict__ deg) {
  int e = blockIdx.x * blockDim.x + threadIdx.x;
  if (e < N_EDGES) atomicAdd(&deg[ei[N_EDGES + e]], 1);
}

__global__ __launch_bounds__(1024) void k_scan(int* __restrict__ deg,
                                               int* __restrict__ row_ptr) {
  __shared__ int sums[1024];
  int t = threadIdx.x;
  const int CH = 20;
  int begin = t * CH;
  int end = begin + CH; if (end > N_NODES) end = N_NODES;
  int loc = 0;
  for (int i = begin; i < end; ++i) loc += deg[i];
  sums[t] = loc;
  __syncthreads();
  for (int off = 1; off < 1024; off <<= 1) {
    int v = (t >= off) ? sums[t - off] : 0;
    __syncthreads();
    sums[t] += v;
    __syncthreads();
  }
  int run = (t > 0) ? sums[t - 1] : 0;
  for (int i = begin; i < end; ++i) {
    int d = deg[i];
    row_ptr[i] = run;
    run += d;
    deg[i] = 0;      // becomes the scatter cursor
  }
  if (t == 1023) row_ptr[N_NODES] = sums[1023];
}

__global__ void k_scatter(const int* __restrict__ ei, const int* __restrict__ row_ptr,
                          int* __restrict__ cursor, int* __restrict__ edge_src) {
  int t = blockIdx.x * blockDim.x + threadIdx.x;
  if (t < N_EDGES) {
    int s = ei[t], d = ei[N_EDGES + t];
    int pos = row_ptr[d] + atomicAdd(&cursor[d], 1);
    edge_src[pos] = s;
  } else if (t < E_TOT) {
    int i = t - N_EDGES;
    int pos = row_ptr[i] + atomicAdd(&cursor[i], 1);
    edge_src[pos] = i;
  }
}

// ---------------- weight prep: W [K][N] f32 -> Bt [N][K] bf16 ----------------
__global__ void k_wt(const float* __restrict__ W, unsigned short* __restrict__ Bt,
                     int K, int N) {
  int idx = blockIdx.x * blockDim.x + threadIdx.x;
  if (idx < N * K) {
    int n = idx / K, k = idx - n * K;
    Bt[idx] = f2b(W[(size_t)k * N + n]);
  }
}

// ---------------- bf16 MFMA GEMM: C = act(A_f32[:, c0:c0+K] @ Bt^T + bias) ----------------
__global__ __launch_bounds__(256) void k_mfma(
    const float* __restrict__ A, int lda, int c0,
    const unsigned short* __restrict__ Bt,
    const float* __restrict__ bias,
    float* __restrict__ Cf, unsigned short* __restrict__ Cb, int ldc,
    int M, int K, int relu) {
  __shared__ unsigned short As[128 * 64];
  __shared__ unsigned short Bs[128 * 64];
  int t = threadIdx.x;
  int m0 = blockIdx.x * 128, n0 = blockIdx.y * 128;
  int w = t >> 6, l = t & 63;
  int wm = (w >> 1) * 64, wn = (w & 1) * 64;
  int lr = l & 15, lhi = l >> 4;
  int r = t >> 1, half = t & 1;

  f32x4 acc[4][4];
  #pragma unroll
  for (int i = 0; i < 4; ++i)
    #pragma unroll
    for (int j = 0; j < 4; ++j)
      acc[i][j] = (f32x4){0.f, 0.f, 0.f, 0.f};

  for (int k0 = 0; k0 < K; k0 += 64) {
    {
      int gm = m0 + r;
      const float* ap = A + (size_t)gm * lda + c0 + k0 + half * 32;
      #pragma unroll
      for (int j = 0; j < 4; ++j) {
        float4 v0, v1;
        if (gm < M) {
          v0 = ((const float4*)ap)[2 * j];
          v1 = ((const float4*)ap)[2 * j + 1];
        } else {
          v0 = make_float4(0.f, 0.f, 0.f, 0.f); v1 = v0;
        }
        uint4 wv;
        wv.x = (unsigned)f2b(v0.x) | ((unsigned)f2b(v0.y) << 16);
        wv.y = (unsigned)f2b(v0.z) | ((unsigned)f2b(v0.w) << 16);
        wv.z = (unsigned)f2b(v1.x) | ((unsigned)f2b(v1.y) << 16);
        wv.w = (unsigned)f2b(v1.z) | ((unsigned)f2b(v1.w) << 16);
        int cb = half * 4 + j;
        *(uint4*)&As[r * 64 + ((cb ^ (r & 7)) << 3)] = wv;
      }
      const unsigned short* bp = Bt + (size_t)(n0 + r) * K + k0 + half * 32;
      #pragma unroll
      for (int j = 0; j < 4; ++j) {
        uint4 wv = ((const uint4*)bp)[j];
        int cb = half * 4 + j;
        *(uint4*)&Bs[r * 64 + ((cb ^ (r & 7)) << 3)] = wv;
      }
    }
    __syncthreads();
    #pragma unroll
    for (int kk = 0; kk < 2; ++kk) {
      short8 af[4], bfr[4];
      #pragma unroll
      for (int i = 0; i < 4; ++i) {
        int row = wm + i * 16 + lr;
        int cb = lhi + kk * 4;
        af[i] = *(const short8*)&As[row * 64 + ((cb ^ (row & 7)) << 3)];
      }
      #pragma unroll
      for (int j = 0; j < 4; ++j) {
        int nn = wn + j * 16 + lr;
        int cb = lhi + kk * 4;
        bfr[j] = *(const short8*)&Bs[nn * 64 + ((cb ^ (nn & 7)) << 3)];
      }
      #pragma unroll
      for (int i = 0; i < 4; ++i)
        #pragma unroll
        for (int j = 0; j < 4; ++j)
          acc[i][j] = __builtin_amdgcn_mfma_f32_16x16x32_bf16(af[i], bfr[j], acc[i][j], 0, 0, 0);
    }
    __syncthreads();
  }

  #pragma unroll
  for (int i = 0; i < 4; ++i) {
    int rowb = m0 + wm + i * 16 + lhi * 4;
    #pragma unroll
    for (int j = 0; j < 4; ++j) {
      int col = n0 + wn + j * 16 + lr;
      float bsv = bias ? bias[col] : 0.f;
      #pragma unroll
      for (int rr = 0; rr < 4; ++rr) {
        int gr = rowb + rr;
        if (gr < M) {
          float v = acc[i][j][rr] + bsv;
          if (relu) v = fmaxf(v, 0.f);
          if (Cf) Cf[(size_t)gr * ldc + col] = v;
          if (Cb) Cb[(size_t)gr * ldc + col] = f2b(v);
        }
      }
    }
  }
}

// ---------------- attention logits from bf16 xh ----------------
__global__ __launch_bounds__(256) void k_attn(const unsigned short* __restrict__ xh,
                                              const float* __restrict__ a_src,
                                              const float* __restrict__ a_dst,
                                              float* __restrict__ als,
                                              float* __restrict__ ald) {
  int node = blockIdx.x;
  int w = threadIdx.x >> 6;       // head
  int lane = threadIdx.x & 63;
  const unsigned short* xp = xh + (size_t)node * 512 + w * 128;
  float x0 = b2f(xp[lane]), x1 = b2f(xp[64 + lane]);
  float ps = x0 * a_src[w * 128 + lane] + x1 * a_src[w * 128 + 64 + lane];
  float pd = x0 * a_dst[w * 128 + lane] + x1 * a_dst[w * 128 + 64 + lane];
  for (int off = 32; off > 0; off >>= 1) {
    ps += __shfl_down(ps, off);
    pd += __shfl_down(pd, off);
  }
  if (lane == 0) {
    als[node * 4 + w] = ps;
    ald[node * 4 + w] = pd;
  }
}

// ---------------- fused GAT aggregation (alpha computed ONCE per edge) ----------------
__global__ __launch_bounds__(128) void k_agg(const unsigned short* __restrict__ xh,
                                             const float* __restrict__ als,
                                             const float* __restrict__ ald,
                                             const int* __restrict__ row_ptr,
                                             const int* __restrict__ edge_src,
                                             const float* __restrict__ bias,
                                             float* __restrict__ h) {
  int node = blockIdx.x;
  int tid = threadIdx.x;  // 0..127
  __shared__ float sp[128][4];    // per-edge exp values
  __shared__ int   ssrc[128];     // per-edge source node
  __shared__ float sredm[8], sreds[8];
  __shared__ float sout[512];     // per-head accumulators for final combine
  __shared__ float red[4 * 128];  // fallback path only
  int begin = row_ptr[node], end = row_ptr[node + 1];
  int deg = end - begin;
  float4 ad4 = *(const float4*)(ald + (size_t)node * 4);
  int wv = tid >> 6;

  if (deg <= 128) {
    // --- one edge per thread ---
    float e0 = -1e30f, e1 = -1e30f, e2 = -1e30f, e3 = -1e30f;
    if (tid < deg) {
      int s = edge_src[begin + tid];
      ssrc[tid] = s;
      float4 a4 = *(const float4*)(als + (size_t)s * 4);
      e0 = lrelu(a4.x + ad4.x); e1 = lrelu(a4.y + ad4.y);
      e2 = lrelu(a4.z + ad4.z); e3 = lrelu(a4.w + ad4.w);
    }
    // wave butterfly max
    float m0 = e0, m1 = e1, m2 = e2, m3 = e3;
    for (int off = 32; off > 0; off >>= 1) {
      m0 = fmaxf(m0, __shfl_xor(m0, off));
      m1 = fmaxf(m1, __shfl_xor(m1, off));
      m2 = fmaxf(m2, __shfl_xor(m2, off));
      m3 = fmaxf(m3, __shfl_xor(m3, off));
    }
    if ((tid & 63) == 0) {
      sredm[wv * 4 + 0] = m0; sredm[wv * 4 + 1] = m1;
      sredm[wv * 4 + 2] = m2; sredm[wv * 4 + 3] = m3;
    }
    __syncthreads();
    m0 = fmaxf(sredm[0], sredm[4]); m1 = fmaxf(sredm[1], sredm[5]);
    m2 = fmaxf(sredm[2], sredm[6]); m3 = fmaxf(sredm[3], sredm[7]);
    // exp once per edge
    float p0 = 0.f, p1 = 0.f, p2 = 0.f, p3 = 0.f;
    if (tid < deg) {
      p0 = __expf(e0 - m0); p1 = __expf(e1 - m1);
      p2 = __expf(e2 - m2); p3 = __expf(e3 - m3);
    }
    *(float4*)&sp[tid][0] = make_float4(p0, p1, p2, p3);
    // wave butterfly sum
    float s0 = p0, s1 = p1, s2 = p2, s3 = p3;
    for (int off = 32; off > 0; off >>= 1) {
      s0 += __shfl_xor(s0, off); s1 += __shfl_xor(s1, off);
      s2 += __shfl_xor(s2, off); s3 += __shfl_xor(s3, off);
    }
    if ((tid & 63) == 0) {
      sreds[wv * 4 + 0] = s0; sreds[wv * 4 + 1] = s1;
      sreds[wv * 4 + 2] = s2; sreds[wv * 4 + 3] = s3;
    }
    __syncthreads();
    float inv0 = 1.f / (sreds[0] + sreds[4] + 1e-16f);
    float inv1 = 1.f / (sreds[1] + sreds[5] + 1e-16f);
    float inv2 = 1.f / (sreds[2] + sreds[6] + 1e-16f);
    float inv3 = 1.f / (sreds[3] + sreds[7] + 1e-16f);

    // --- phase C: thread = (head, 4 channels); wave reads 512 contiguous B/edge ---
    int hsel = tid >> 5;
    int c4 = (tid & 31) << 2;
    const unsigned short* xbase = xh + hsel * 128 + c4;
    float a0 = 0.f, a1 = 0.f, a2 = 0.f, a3 = 0.f;
    for (int k = 0; k < deg; ++k) {
      int s = ssrc[k];
      float p = sp[k][hsel];
      ushort4 xv = *(const ushort4*)(xbase + (size_t)s * 512);
      a0 += p * b2f(xv.x); a1 += p * b2f(xv.y);
      a2 += p * b2f(xv.z); a3 += p * b2f(xv.w);
    }
    float invh = hsel < 2 ? (hsel == 0 ? inv0 : inv1) : (hsel == 2 ? inv2 : inv3);
    *(float4*)&sout[hsel * 128 + c4] =
        make_float4(a0 * invh, a1 * invh, a2 * invh, a3 * invh);
    __syncthreads();
    float val = 0.25f * (sout[tid] + sout[128 + tid] + sout[256 + tid] + sout[384 + tid])
                + bias[tid];
    val = val > 0.f ? val : __expf(val) - 1.f;  // elu
    size_t o = (size_t)node * 128 + tid;
    h[o] = val + h[o];
    return;
  }

  // ---------- generic fallback (deg > 128; statistically never here) ----------
  float lm0 = -1e30f, lm1 = -1e30f, lm2 = -1e30f, lm3 = -1e30f;
  for (int idx = begin + tid; idx < end; idx += 128) {
    int s = edge_src[idx];
    float4 a4 = *(const float4*)(als + (size_t)s * 4);
    lm0 = fmaxf(lm0, lrelu(a4.x + ad4.x));
    lm1 = fmaxf(lm1, lrelu(a4.y + ad4.y));
    lm2 = fmaxf(lm2, lrelu(a4.z + ad4.z));
    lm3 = fmaxf(lm3, lrelu(a4.w + ad4.w));
  }
  red[tid] = lm0; red[128 + tid] = lm1; red[256 + tid] = lm2; red[384 + tid] = lm3;
  __syncthreads();
  for (int off = 64; off > 0; off >>= 1) {
    if (tid < off) {
      red[tid]       = fmaxf(red[tid],       red[tid + off]);
      red[128 + tid] = fmaxf(red[128 + tid], red[128 + tid + off]);
      red[256 + tid] = fmaxf(red[256 + tid], red[256 + tid + off]);
      red[384 + tid] = fmaxf(red[384 + tid], red[384 + tid + off]);
    }
    __syncthreads();
  }
  float m0 = red[0], m1 = red[128], m2 = red[256], m3 = red[384];
  __syncthreads();
  float ls0 = 0.f, ls1 = 0.f, ls2 = 0.f, ls3 = 0.f;
  for (int idx = begin + tid; idx < end; idx += 128) {
    int s = edge_src[idx];
    float4 a4 = *(const float4*)(als + (size_t)s * 4);
    ls0 += __expf(lrelu(a4.x + ad4.x) - m0);
    ls1 += __expf(lrelu(a4.y + ad4.y) - m1);
    ls2 += __expf(lrelu(a4.z + ad4.z) - m2);
    ls3 += __expf(lrelu(a4.w + ad4.w) - m3);
  }
  red[tid] = ls0; red[128 + tid] = ls1; red[256 + tid] = ls2; red[384 + tid] = ls3;
  __syncthreads();
  for (int off = 64; off > 0; off >>= 1) {
    if (tid < off) {
      red[tid]       += red[tid + off];
      red[128 + tid] += red[128 + tid + off];
      red[256 + tid] += red[256 + tid + off];
      red[384 + tid] += red[384 + tid + off];
    }
    __syncthreads();
  }
  float inv0 = 1.f / (red[0]   + 1e-16f);
  float inv1 = 1.f / (red[128] + 1e-16f);
  float inv2 = 1.f / (red[256] + 1e-16f);
  float inv3 = 1.f / (red[384] + 1e-16f);
  float acc0 = 0.f, acc1 = 0.f, acc2 = 0.f, acc3 = 0.f;
  for (int idx = begin; idx < end; ++idx) {
    int s = edge_src[idx];
    float4 a4 = *(const float4*)(als + (size_t)s * 4);
    float al0 = __expf(lrelu(a4.x + ad4.x) - m0) * inv0;
    float al1 = __expf(lrelu(a4.y + ad4.y) - m1) * inv1;
    float al2 = __expf(lrelu(a4.z + ad4.z) - m2) * inv2;
    float al3 = __expf(lrelu(a4.w + ad4.w) - m3) * inv3;
    const unsigned short* xr = xh + (size_t)s * 512;
    acc0 += al0 * b2f(xr[tid]);
    acc1 += al1 * b2f(xr[128 + tid]);
    acc2 += al2 * b2f(xr[256 + tid]);
    acc3 += al3 * b2f(xr[384 + tid]);
  }
  float val = 0.25f * (acc0 + acc1 + acc2 + acc3) + bias[tid];
  val = val > 0.f ? val : __expf(val) - 1.f;
  size_t o = (size_t)node * 128 + tid;
  h[o] = val + h[o];
}

// ---------------- modal gating + final embedding ----------------
__global__ __launch_bounds__(128) void k_modal(const float* __restrict__ hv,
                                               const float* __restrict__ ht,
                                               const float* __restrict__ mw,
                                               const float* __restrict__ mb,
                                               float* __restrict__ out) {
  int node = blockIdx.x, t = threadIdx.x;
  __shared__ float red[128];
  float a = hv[(size_t)node * 128 + t];
  float b = ht[(size_t)node * 128 + t];
  red[t] = a * mw[t] + b * mw[128 + t];
  __syncthreads();
  for (int off = 64; off > 0; off >>= 1) {
    if (t < off) red[t] += red[t + off];
    __syncthreads();
  }
  float beta = 1.f / (1.f + expf(-(red[0] + mb[0])));
  out[(size_t)node * 128 + t] = beta * a + (1.f - beta) * b;
}

extern "C" void kernel_launch(void* const* d_in, const int* in_sizes, int n_in,
                              void* d_out, int out_size, void* d_ws, size_t ws_size,
                              hipStream_t stream) {
  const float* x    = (const float*)d_in[0];
  const int*   ei   = (const int*)d_in[1];
  const float* vpw  = (const float*)d_in[2];
  const float* vpb  = (const float*)d_in[3];
  const float* tpw  = (const float*)d_in[4];
  const float* tpb  = (const float*)d_in[5];
  const float* vgw  = (const float*)d_in[6];
  const float* vgas = (const float*)d_in[7];
  const float* vgad = (const float*)d_in[8];
  const float* vgb  = (const float*)d_in[9];
  const float* tgw  = (const float*)d_in[10];
  const float* tgas = (const float*)d_in[11];
  const float* tgad = (const float*)d_in[12];
  const float* tgb  = (const float*)d_in[13];
  const float* mw   = (const float*)d_in[14];
  const float* mb   = (const float*)d_in[15];
  const float* vhw  = (const float*)d_in[16];
  const float* vhb  = (const float*)d_in[17];
  const float* thw  = (const float*)d_in[18];
  const float* thb  = (const float*)d_in[19];
  float* out = (float*)d_out;

  char* ws = (char*)d_ws;
  float*          h_v      = (float*)(ws);                         // 10,240,000 B
  float*          h_t      = (float*)(ws + 10240000);              // 10,240,000 B
  unsigned short* xhb      = (unsigned short*)(ws + 20480000);     // 20,480,000 B
  float*          als      = (float*)(ws + 40960000);              //    320,000 B
  float*          ald      = (float*)(ws + 41280000);              //    320,000 B
  int*            row_ptr  = (int*)  (ws + 41600000);              //     80,016 B
  int*            deg      = (int*)  (ws + 41680016);              //     80,000 B
  int*            edge_src = (int*)  (ws + 41760016);              //  1,360,000 B
  unsigned short* bt       = (unsigned short*)(ws + 43120016);     //    884,736 B

  unsigned short* bt_vp = bt;            // [128][768]
  unsigned short* bt_tp = bt + 98304;    // [128][384]
  unsigned short* bt_vg = bt + 147456;   // 2 x [512][128]
  unsigned short* bt_tg = bt + 278528;   // 2 x [512][128]
  unsigned short* bt_vh = bt + 409600;   // [128][128]
  unsigned short* bt_th = bt + 425984;   // [128][128]

  // weight prep
  k_wt<<<(98304 + 255) / 256, 256, 0, stream>>>(vpw, bt_vp, 768, 128);
  k_wt<<<(49152 + 255) / 256, 256, 0, stream>>>(tpw, bt_tp, 384, 128);
  for (int L = 0; L < 2; ++L) {
    k_wt<<<(65536 + 255) / 256, 256, 0, stream>>>(vgw + (size_t)L * 65536, bt_vg + (size_t)L * 65536, 128, 512);
    k_wt<<<(65536 + 255) / 256, 256, 0, stream>>>(tgw + (size_t)L * 65536, bt_tg + (size_t)L * 65536, 128, 512);
  }
  k_wt<<<(16384 + 255) / 256, 256, 0, stream>>>(vhw, bt_vh, 128, 128);
  k_wt<<<(16384 + 255) / 256, 256, 0, stream>>>(thw, bt_th, 128, 128);

  // CSR build (includes self loops)
  k_init_deg<<<(N_NODES + 255) / 256, 256, 0, stream>>>(deg);
  k_hist<<<(N_EDGES + 255) / 256, 256, 0, stream>>>(ei, deg);
  k_scan<<<1, 1024, 0, stream>>>(deg, row_ptr);
  k_scatter<<<(E_TOT + 255) / 256, 256, 0, stream>>>(ei, row_ptr, deg, edge_src);

  // input projections (ReLU, f32 out)
  dim3 gp(157, 1);
  k_mfma<<<gp, 256, 0, stream>>>(x, 1152, 0,   bt_vp, vpb, h_v, nullptr, HID, N_NODES, 768, 1);
  k_mfma<<<gp, 256, 0, stream>>>(x, 1152, 768, bt_tp, tpb, h_t, nullptr, HID, N_NODES, 384, 1);

  // GAT layers
  dim3 gx(157, 4);
  for (int L = 0; L < 2; ++L) {
    k_mfma<<<gx, 256, 0, stream>>>(h_v, HID, 0, bt_vg + (size_t)L * 65536, nullptr,
                                   nullptr, xhb, 512, N_NODES, HID, 0);
    k_attn<<<N_NODES, 256, 0, stream>>>(xhb, vgas + L * 512, vgad + L * 512, als, ald);
    k_agg<<<N_NODES, 128, 0, stream>>>(xhb, als, ald, row_ptr, edge_src, vgb + L * HID, h_v);

    k_mfma<<<gx, 256, 0, stream>>>(h_t, HID, 0, bt_tg + (size_t)L * 65536, nullptr,
                                   nullptr, xhb, 512, N_NODES, HID, 0);
    k_attn<<<N_NODES, 256, 0, stream>>>(xhb, tgas + L * 512, tgad + L * 512, als, ald);
    k_agg<<<N_NODES, 128, 0, stream>>>(xhb, als, ald, row_ptr, edge_src, tgb + L * HID, h_t);
  }

  // epilogue
  k_modal<<<N_NODES, 128, 0, stream>>>(h_v, h_t, mw, mb, out);
  k_mfma<<<gp, 256, 0, stream>>>(h_v, HID, 0, bt_vh, vhb, out + 2560000, nullptr, HID, N_NODES, HID, 1);
  k_mfma<<<gp, 256, 0, stream>>>(h_t, HID, 0, bt_th, thb, out + 5120000, nullptr, HID, N_NODES, HID, 1);
}

// Round 4
// 475.282 us; speedup vs baseline: 2.0848x; 1.1575x over previous
//
#include <hip/hip_runtime.h>
#include <math.h>

#define N_NODES 20000
#define N_EDGES 320000
#define E_TOT   (N_EDGES + N_NODES)
#define HID     128
#define NEG_SLOPE 0.2f
#define MTILES  313   // ceil(20000/64)

typedef __attribute__((ext_vector_type(8))) short short8;
typedef __attribute__((ext_vector_type(4))) float f32x4;

__device__ __forceinline__ unsigned short f2b(float f) {
  unsigned u = __builtin_bit_cast(unsigned, f);
  return (unsigned short)((u + 0x7fffu + ((u >> 16) & 1u)) >> 16);
}
__device__ __forceinline__ float b2f(unsigned short h) {
  unsigned u = ((unsigned)h) << 16;
  return __builtin_bit_cast(float, u);
}
__device__ __forceinline__ float lrelu(float x) { return x > 0.f ? x : NEG_SLOPE * x; }

// ---------------- CSR build ----------------
__global__ void k_init_deg(int* __restrict__ deg) {
  int i = blockIdx.x * blockDim.x + threadIdx.x;
  if (i < N_NODES) deg[i] = 1;  // self loop
}

__global__ void k_hist(const int* __restrict__ ei, int* __restrict__ deg) {
  int e = blockIdx.x * blockDim.x + threadIdx.x;
  if (e < N_EDGES) atomicAdd(&deg[ei[N_EDGES + e]], 1);
}

__global__ __launch_bounds__(1024) void k_scan(int* __restrict__ deg,
                                               int* __restrict__ row_ptr) {
  __shared__ int sums[1024];
  int t = threadIdx.x;
  const int CH = 20;
  int begin = t * CH;
  int end = begin + CH; if (end > N_NODES) end = N_NODES;
  int loc = 0;
  for (int i = begin; i < end; ++i) loc += deg[i];
  sums[t] = loc;
  __syncthreads();
  for (int off = 1; off < 1024; off <<= 1) {
    int v = (t >= off) ? sums[t - off] : 0;
    __syncthreads();
    sums[t] += v;
    __syncthreads();
  }
  int run = (t > 0) ? sums[t - 1] : 0;
  for (int i = begin; i < end; ++i) {
    int d = deg[i];
    row_ptr[i] = run;
    run += d;
    deg[i] = 0;      // becomes the scatter cursor
  }
  if (t == 1023) row_ptr[N_NODES] = sums[1023];
}

__global__ void k_scatter(const int* __restrict__ ei, const int* __restrict__ row_ptr,
                          int* __restrict__ cursor, int* __restrict__ edge_src) {
  int t = blockIdx.x * blockDim.x + threadIdx.x;
  if (t < N_EDGES) {
    int s = ei[t], d = ei[N_EDGES + t];
    int pos = row_ptr[d] + atomicAdd(&cursor[d], 1);
    edge_src[pos] = s;
  } else if (t < E_TOT) {
    int i = t - N_EDGES;
    int pos = row_ptr[i] + atomicAdd(&cursor[i], 1);
    edge_src[pos] = i;
  }
}

// ---------------- merged weight prep: 8 jobs, W [K][N] f32 -> Bt [N][K] bf16 ----------------
struct WtJobs {
  const float* src[8];
  unsigned short* dst[8];
  int K[8], N[8], blk_end[8];
};

__global__ void k_wt_all(WtJobs jb) {
  int b = blockIdx.x;
  int seg = 0;
  while (b >= jb.blk_end[seg]) ++seg;
  int base = seg ? jb.blk_end[seg - 1] : 0;
  int idx = (b - base) * 256 + threadIdx.x;
  int K = jb.K[seg], N = jb.N[seg];
  if (idx < N * K) {
    int n = idx / K, k = idx - n * K;
    jb.dst[seg][idx] = f2b(jb.src[seg][(size_t)k * N + n]);
  }
}

// ---------------- GEMM core: 64x128 tile, 4 waves (2x2), BK=64, reg-prefetch ----------------
// MODE 0: f32 out + bias + relu.  MODE 1: bf16 out (LDS-coalesced) + fused attn logits.
template<int MODE>
__device__ __forceinline__ void gemm_core(
    const float* __restrict__ A, int lda, int c0,
    const unsigned short* __restrict__ Bt,
    const float* __restrict__ bias,
    float* __restrict__ Cf, unsigned short* __restrict__ Cb, int ldc,
    int M, int K, int m0, int n0,
    const float* __restrict__ asrc, const float* __restrict__ adst,
    float* __restrict__ als, float* __restrict__ ald, int head) {
  __shared__ unsigned short sAB[64 * 64 + 128 * 64];  // As | Bs ; reused as C-tile
  __shared__ float attS[64 * 2], attD[64 * 2];
  unsigned short* As = sAB;
  unsigned short* Bs = sAB + 64 * 64;

  int t = threadIdx.x;
  int w = t >> 6, l = t & 63;
  int wr = w >> 1, wc = w & 1;
  int lr = l & 15, lhi = l >> 4;

  // staging maps
  int arow = t >> 2, aq = t & 3;          // A: 64 rows x (4 threads of 16 f32)
  int brow = t >> 1, bhalf = t & 1;       // B: 128 rows x (2 threads of 32 bf16)
  int agr = m0 + arow; if (agr > M - 1) agr = M - 1;   // clamp: rows OOB only feed guarded outputs
  const float* aptr = A + (size_t)agr * lda + c0 + aq * 16;
  const unsigned short* bptr = Bt + (size_t)(n0 + brow) * K + bhalf * 32;

  f32x4 acc[2][4];
  #pragma unroll
  for (int i = 0; i < 2; ++i)
    #pragma unroll
    for (int j = 0; j < 4; ++j) acc[i][j] = (f32x4){0.f, 0.f, 0.f, 0.f};

  float4 ar[4];
  uint4  br[4];
  #pragma unroll
  for (int p = 0; p < 4; ++p) ar[p] = ((const float4*)aptr)[p];
  #pragma unroll
  for (int p = 0; p < 4; ++p) br[p] = ((const uint4*)bptr)[p];

  for (int k0 = 0; k0 < K; k0 += 64) {
    // regs -> LDS (A converts f32->bf16)
    uint4 aw0, aw1;
    aw0.x = (unsigned)f2b(ar[0].x) | ((unsigned)f2b(ar[0].y) << 16);
    aw0.y = (unsigned)f2b(ar[0].z) | ((unsigned)f2b(ar[0].w) << 16);
    aw0.z = (unsigned)f2b(ar[1].x) | ((unsigned)f2b(ar[1].y) << 16);
    aw0.w = (unsigned)f2b(ar[1].z) | ((unsigned)f2b(ar[1].w) << 16);
    aw1.x = (unsigned)f2b(ar[2].x) | ((unsigned)f2b(ar[2].y) << 16);
    aw1.y = (unsigned)f2b(ar[2].z) | ((unsigned)f2b(ar[2].w) << 16);
    aw1.z = (unsigned)f2b(ar[3].x) | ((unsigned)f2b(ar[3].y) << 16);
    aw1.w = (unsigned)f2b(ar[3].z) | ((unsigned)f2b(ar[3].w) << 16);
    {
      int cb0 = aq * 2, cb1 = aq * 2 + 1;
      *(uint4*)&As[arow * 64 + ((cb0 ^ (arow & 7)) << 3)] = aw0;
      *(uint4*)&As[arow * 64 + ((cb1 ^ (arow & 7)) << 3)] = aw1;
    }
    #pragma unroll
    for (int p = 0; p < 4; ++p) {
      int cb = bhalf * 4 + p;
      *(uint4*)&Bs[brow * 64 + ((cb ^ (brow & 7)) << 3)] = br[p];
    }
    __syncthreads();
    // prefetch next K-step while this one computes
    if (k0 + 64 < K) {
      #pragma unroll
      for (int p = 0; p < 4; ++p) ar[p] = ((const float4*)(aptr + k0 + 64))[p];
      #pragma unroll
      for (int p = 0; p < 4; ++p) br[p] = ((const uint4*)(bptr + k0 + 64))[p];
    }
    #pragma unroll
    for (int kk = 0; kk < 2; ++kk) {
      short8 af[2], bfr[4];
      int cbf = lhi + kk * 4;
      #pragma unroll
      for (int i = 0; i < 2; ++i) {
        int row = wr * 32 + i * 16 + lr;
        af[i] = *(const short8*)&As[row * 64 + ((cbf ^ (row & 7)) << 3)];
      }
      #pragma unroll
      for (int j = 0; j < 4; ++j) {
        int nn = wc * 64 + j * 16 + lr;
        bfr[j] = *(const short8*)&Bs[nn * 64 + ((cbf ^ (nn & 7)) << 3)];
      }
      #pragma unroll
      for (int i = 0; i < 2; ++i)
        #pragma unroll
        for (int j = 0; j < 4; ++j)
          acc[i][j] = __builtin_amdgcn_mfma_f32_16x16x32_bf16(af[i], bfr[j], acc[i][j], 0, 0, 0);
    }
    __syncthreads();
  }

  if (MODE == 0) {
    // direct f32 stores (+bias, relu)
    #pragma unroll
    for (int i = 0; i < 2; ++i) {
      #pragma unroll
      for (int j = 0; j < 4; ++j) {
        int col = n0 + wc * 64 + j * 16 + lr;
        float bsv = bias[col - n0];
        #pragma unroll
        for (int rr = 0; rr < 4; ++rr) {
          int gr = m0 + wr * 32 + i * 16 + lhi * 4 + rr;
          if (gr < M) {
            float v = acc[i][j][rr] + bsv;
            v = fmaxf(v, 0.f);
            Cf[(size_t)gr * ldc + col] = v;
          }
        }
      }
    }
  } else {
    // ---- fused attention logits (from bf16-rounded values, matching stored xh) ----
    float asv[4], adv[4];
    #pragma unroll
    for (int j = 0; j < 4; ++j) {
      int col = wc * 64 + j * 16 + lr;
      asv[j] = asrc[col];
      adv[j] = adst[col];
    }
    #pragma unroll
    for (int i = 0; i < 2; ++i) {
      #pragma unroll
      for (int rr = 0; rr < 4; ++rr) {
        float ss = 0.f, sd = 0.f;
        #pragma unroll
        for (int j = 0; j < 4; ++j) {
          float v = b2f(f2b(acc[i][j][rr]));
          ss += v * asv[j];
          sd += v * adv[j];
        }
        ss += __shfl_xor(ss, 1); sd += __shfl_xor(sd, 1);
        ss += __shfl_xor(ss, 2); sd += __shfl_xor(sd, 2);
        ss += __shfl_xor(ss, 4); sd += __shfl_xor(sd, 4);
        ss += __shfl_xor(ss, 8); sd += __shfl_xor(sd, 8);
        if (lr == 0) {
          int row = wr * 32 + i * 16 + lhi * 4 + rr;
          attS[row * 2 + wc] = ss;
          attD[row * 2 + wc] = sd;
        }
      }
    }
    __syncthreads();   // attS/D ready; As/Bs free for reuse
    // ---- C-tile to LDS (bf16), then coalesced global write ----
    unsigned short* Ct = sAB;  // [64][128]
    #pragma unroll
    for (int i = 0; i < 2; ++i)
      #pragma unroll
      for (int j = 0; j < 4; ++j) {
        int col = wc * 64 + j * 16 + lr;
        #pragma unroll
        for (int rr = 0; rr < 4; ++rr) {
          int row = wr * 32 + i * 16 + lhi * 4 + rr;
          Ct[row * 128 + col] = f2b(acc[i][j][rr]);
        }
      }
    __syncthreads();
    if (t < 64) {
      int gr = m0 + t;
      if (gr < M) {
        als[gr * 4 + head] = attS[t * 2] + attS[t * 2 + 1];
        ald[gr * 4 + head] = attD[t * 2] + attD[t * 2 + 1];
      }
    }
    int crow = t >> 2, cq = t & 3;
    int gr = m0 + crow;
    if (gr < M) {
      uint4* gdst = (uint4*)(Cb + (size_t)gr * ldc + n0 + cq * 32);
      const uint4* lsrc = (const uint4*)&Ct[crow * 128 + cq * 32];
      #pragma unroll
      for (int p = 0; p < 4; ++p) gdst[p] = lsrc[p];
    }
  }
}

// z-merged projections: y=0 vis (K=768), y=1 txt (K=384)
__global__ __launch_bounds__(256) void k_proj(
    const float* __restrict__ x,
    const unsigned short* __restrict__ btv, const unsigned short* __restrict__ btt,
    const float* __restrict__ vb, const float* __restrict__ tb,
    float* __restrict__ hv, float* __restrict__ ht) {
  int m0 = blockIdx.x * 64;
  const float* A = x;
  int c0, K;
  const unsigned short* Bt;
  const float* bias;
  float* Cf;
  if (blockIdx.y == 0) { c0 = 0;   K = 768; Bt = btv; bias = vb; Cf = hv; }
  else                 { c0 = 768; K = 384; Bt = btt; bias = tb; Cf = ht; }
  gemm_core<0>(A, 1152, c0, Bt, bias, Cf, nullptr, 128, N_NODES, K, m0, 0,
               nullptr, nullptr, nullptr, nullptr, 0);
}

// layer GEMM + fused attention; y = head
__global__ __launch_bounds__(256) void k_layer(
    const float* __restrict__ h, const unsigned short* __restrict__ bt,
    const float* __restrict__ asrc, const float* __restrict__ adst,
    unsigned short* __restrict__ xhb, float* __restrict__ als, float* __restrict__ ald) {
  int m0 = blockIdx.x * 64;
  int head = blockIdx.y;
  gemm_core<1>(h, 128, 0, bt, nullptr, nullptr, xhb, 512, N_NODES, 128, m0, head * 128,
               asrc + head * 128, adst + head * 128, als, ald, head);
}

// z-merged head GEMMs: y=0 vision head, y=1 text head
__global__ __launch_bounds__(256) void k_head(
    const float* __restrict__ hv, const float* __restrict__ ht,
    const unsigned short* __restrict__ btvh, const unsigned short* __restrict__ btth,
    const float* __restrict__ vhb, const float* __restrict__ thb,
    float* __restrict__ out) {
  int m0 = blockIdx.x * 64;
  const float* A;
  const unsigned short* Bt;
  const float* bias;
  float* Cf;
  if (blockIdx.y == 0) { A = hv; Bt = btvh; bias = vhb; Cf = out + 2560000; }
  else                 { A = ht; Bt = btth; bias = thb; Cf = out + 5120000; }
  gemm_core<0>(A, 128, 0, Bt, bias, Cf, nullptr, 128, N_NODES, 128, m0, 0,
               nullptr, nullptr, nullptr, nullptr, 0);
}

// ---------------- fused GAT aggregation (alpha once per edge) ----------------
__global__ __launch_bounds__(128) void k_agg(const unsigned short* __restrict__ xh,
                                             const float* __restrict__ als,
                                             const float* __restrict__ ald,
                                             const int* __restrict__ row_ptr,
                                             const int* __restrict__ edge_src,
                                             const float* __restrict__ bias,
                                             float* __restrict__ h) {
  int node = blockIdx.x;
  int tid = threadIdx.x;  // 0..127
  __shared__ float sp[128][4];
  __shared__ int   ssrc[128];
  __shared__ float sredm[8], sreds[8];
  __shared__ float sout[512];
  __shared__ float red[4 * 128];
  int begin = row_ptr[node], end = row_ptr[node + 1];
  int deg = end - begin;
  float4 ad4 = *(const float4*)(ald + (size_t)node * 4);
  int wv = tid >> 6;

  if (deg <= 128) {
    float e0 = -1e30f, e1 = -1e30f, e2 = -1e30f, e3 = -1e30f;
    if (tid < deg) {
      int s = edge_src[begin + tid];
      ssrc[tid] = s;
      float4 a4 = *(const float4*)(als + (size_t)s * 4);
      e0 = lrelu(a4.x + ad4.x); e1 = lrelu(a4.y + ad4.y);
      e2 = lrelu(a4.z + ad4.z); e3 = lrelu(a4.w + ad4.w);
    }
    float m0 = e0, m1 = e1, m2 = e2, m3 = e3;
    for (int off = 32; off > 0; off >>= 1) {
      m0 = fmaxf(m0, __shfl_xor(m0, off));
      m1 = fmaxf(m1, __shfl_xor(m1, off));
      m2 = fmaxf(m2, __shfl_xor(m2, off));
      m3 = fmaxf(m3, __shfl_xor(m3, off));
    }
    if ((tid & 63) == 0) {
      sredm[wv * 4 + 0] = m0; sredm[wv * 4 + 1] = m1;
      sredm[wv * 4 + 2] = m2; sredm[wv * 4 + 3] = m3;
    }
    __syncthreads();
    m0 = fmaxf(sredm[0], sredm[4]); m1 = fmaxf(sredm[1], sredm[5]);
    m2 = fmaxf(sredm[2], sredm[6]); m3 = fmaxf(sredm[3], sredm[7]);
    float p0 = 0.f, p1 = 0.f, p2 = 0.f, p3 = 0.f;
    if (tid < deg) {
      p0 = __expf(e0 - m0); p1 = __expf(e1 - m1);
      p2 = __expf(e2 - m2); p3 = __expf(e3 - m3);
    }
    *(float4*)&sp[tid][0] = make_float4(p0, p1, p2, p3);
    float s0 = p0, s1 = p1, s2 = p2, s3 = p3;
    for (int off = 32; off > 0; off >>= 1) {
      s0 += __shfl_xor(s0, off); s1 += __shfl_xor(s1, off);
      s2 += __shfl_xor(s2, off); s3 += __shfl_xor(s3, off);
    }
    if ((tid & 63) == 0) {
      sreds[wv * 4 + 0] = s0; sreds[wv * 4 + 1] = s1;
      sreds[wv * 4 + 2] = s2; sreds[wv * 4 + 3] = s3;
    }
    __syncthreads();
    float inv0 = 1.f / (sreds[0] + sreds[4] + 1e-16f);
    float inv1 = 1.f / (sreds[1] + sreds[5] + 1e-16f);
    float inv2 = 1.f / (sreds[2] + sreds[6] + 1e-16f);
    float inv3 = 1.f / (sreds[3] + sreds[7] + 1e-16f);

    int hsel = tid >> 5;
    int c4 = (tid & 31) << 2;
    const unsigned short* xbase = xh + hsel * 128 + c4;
    float a0 = 0.f, a1 = 0.f, a2 = 0.f, a3 = 0.f;
    for (int k = 0; k < deg; ++k) {
      int s = ssrc[k];
      float p = sp[k][hsel];
      ushort4 xv = *(const ushort4*)(xbase + (size_t)s * 512);
      a0 += p * b2f(xv.x); a1 += p * b2f(xv.y);
      a2 += p * b2f(xv.z); a3 += p * b2f(xv.w);
    }
    float invh = hsel < 2 ? (hsel == 0 ? inv0 : inv1) : (hsel == 2 ? inv2 : inv3);
    *(float4*)&sout[hsel * 128 + c4] =
        make_float4(a0 * invh, a1 * invh, a2 * invh, a3 * invh);
    __syncthreads();
    float val = 0.25f * (sout[tid] + sout[128 + tid] + sout[256 + tid] + sout[384 + tid])
                + bias[tid];
    val = val > 0.f ? val : __expf(val) - 1.f;  // elu
    size_t o = (size_t)node * 128 + tid;
    h[o] = val + h[o];
    return;
  }

  // generic fallback (deg > 128)
  float lm0 = -1e30f, lm1 = -1e30f, lm2 = -1e30f, lm3 = -1e30f;
  for (int idx = begin + tid; idx < end; idx += 128) {
    int s = edge_src[idx];
    float4 a4 = *(const float4*)(als + (size_t)s * 4);
    lm0 = fmaxf(lm0, lrelu(a4.x + ad4.x));
    lm1 = fmaxf(lm1, lrelu(a4.y + ad4.y));
    lm2 = fmaxf(lm2, lrelu(a4.z + ad4.z));
    lm3 = fmaxf(lm3, lrelu(a4.w + ad4.w));
  }
  red[tid] = lm0; red[128 + tid] = lm1; red[256 + tid] = lm2; red[384 + tid] = lm3;
  __syncthreads();
  for (int off = 64; off > 0; off >>= 1) {
    if (tid < off) {
      red[tid]       = fmaxf(red[tid],       red[tid + off]);
      red[128 + tid] = fmaxf(red[128 + tid], red[128 + tid + off]);
      red[256 + tid] = fmaxf(red[256 + tid], red[256 + tid + off]);
      red[384 + tid] = fmaxf(red[384 + tid], red[384 + tid + off]);
    }
    __syncthreads();
  }
  float m0 = red[0], m1 = red[128], m2 = red[256], m3 = red[384];
  __syncthreads();
  float ls0 = 0.f, ls1 = 0.f, ls2 = 0.f, ls3 = 0.f;
  for (int idx = begin + tid; idx < end; idx += 128) {
    int s = edge_src[idx];
    float4 a4 = *(const float4*)(als + (size_t)s * 4);
    ls0 += __expf(lrelu(a4.x + ad4.x) - m0);
    ls1 += __expf(lrelu(a4.y + ad4.y) - m1);
    ls2 += __expf(lrelu(a4.z + ad4.z) - m2);
    ls3 += __expf(lrelu(a4.w + ad4.w) - m3);
  }
  red[tid] = ls0; red[128 + tid] = ls1; red[256 + tid] = ls2; red[384 + tid] = ls3;
  __syncthreads();
  for (int off = 64; off > 0; off >>= 1) {
    if (tid < off) {
      red[tid]       += red[tid + off];
      red[128 + tid] += red[128 + tid + off];
      red[256 + tid] += red[256 + tid + off];
      red[384 + tid] += red[384 + tid + off];
    }
    __syncthreads();
  }
  float inv0 = 1.f / (red[0]   + 1e-16f);
  float inv1 = 1.f / (red[128] + 1e-16f);
  float inv2 = 1.f / (red[256] + 1e-16f);
  float inv3 = 1.f / (red[384] + 1e-16f);
  float acc0 = 0.f, acc1 = 0.f, acc2 = 0.f, acc3 = 0.f;
  for (int idx = begin; idx < end; ++idx) {
    int s = edge_src[idx];
    float4 a4 = *(const float4*)(als + (size_t)s * 4);
    float al0 = __expf(lrelu(a4.x + ad4.x) - m0) * inv0;
    float al1 = __expf(lrelu(a4.y + ad4.y) - m1) * inv1;
    float al2 = __expf(lrelu(a4.z + ad4.z) - m2) * inv2;
    float al3 = __expf(lrelu(a4.w + ad4.w) - m3) * inv3;
    const unsigned short* xr = xh + (size_t)s * 512;
    acc0 += al0 * b2f(xr[tid]);
    acc1 += al1 * b2f(xr[128 + tid]);
    acc2 += al2 * b2f(xr[256 + tid]);
    acc3 += al3 * b2f(xr[384 + tid]);
  }
  float val = 0.25f * (acc0 + acc1 + acc2 + acc3) + bias[tid];
  val = val > 0.f ? val : __expf(val) - 1.f;
  size_t o = (size_t)node * 128 + tid;
  h[o] = val + h[o];
}

// ---------------- modal gating ----------------
__global__ __launch_bounds__(128) void k_modal(const float* __restrict__ hv,
                                               const float* __restrict__ ht,
                                               const float* __restrict__ mw,
                                               const float* __restrict__ mb,
                                               float* __restrict__ out) {
  int node = blockIdx.x, t = threadIdx.x;
  __shared__ float red[128];
  float a = hv[(size_t)node * 128 + t];
  float b = ht[(size_t)node * 128 + t];
  red[t] = a * mw[t] + b * mw[128 + t];
  __syncthreads();
  for (int off = 64; off > 0; off >>= 1) {
    if (t < off) red[t] += red[t + off];
    __syncthreads();
  }
  float beta = 1.f / (1.f + expf(-(red[0] + mb[0])));
  out[(size_t)node * 128 + t] = beta * a + (1.f - beta) * b;
}

extern "C" void kernel_launch(void* const* d_in, const int* in_sizes, int n_in,
                              void* d_out, int out_size, void* d_ws, size_t ws_size,
                              hipStream_t stream) {
  const float* x    = (const float*)d_in[0];
  const int*   ei   = (const int*)d_in[1];
  const float* vpw  = (const float*)d_in[2];
  const float* vpb  = (const float*)d_in[3];
  const float* tpw  = (const float*)d_in[4];
  const float* tpb  = (const float*)d_in[5];
  const float* vgw  = (const float*)d_in[6];
  const float* vgas = (const float*)d_in[7];
  const float* vgad = (const float*)d_in[8];
  const float* vgb  = (const float*)d_in[9];
  const float* tgw  = (const float*)d_in[10];
  const float* tgas = (const float*)d_in[11];
  const float* tgad = (const float*)d_in[12];
  const float* tgb  = (const float*)d_in[13];
  const float* mw   = (const float*)d_in[14];
  const float* mb   = (const float*)d_in[15];
  const float* vhw  = (const float*)d_in[16];
  const float* vhb  = (const float*)d_in[17];
  const float* thw  = (const float*)d_in[18];
  const float* thb  = (const float*)d_in[19];
  float* out = (float*)d_out;

  char* ws = (char*)d_ws;
  float*          h_v      = (float*)(ws);                         // 10,240,000 B
  float*          h_t      = (float*)(ws + 10240000);              // 10,240,000 B
  unsigned short* xhb      = (unsigned short*)(ws + 20480000);     // 20,480,000 B
  float*          als      = (float*)(ws + 40960000);              //    320,000 B
  float*          ald      = (float*)(ws + 41280000);              //    320,000 B
  int*            row_ptr  = (int*)  (ws + 41600000);              //     80,016 B
  int*            deg      = (int*)  (ws + 41680016);              //     80,000 B
  int*            edge_src = (int*)  (ws + 41760016);              //  1,360,000 B
  unsigned short* bt       = (unsigned short*)(ws + 43120016);     //    884,736 B

  unsigned short* bt_vp = bt;            // [128][768]
  unsigned short* bt_tp = bt + 98304;    // [128][384]
  unsigned short* bt_vg = bt + 147456;   // 2 x [512][128]
  unsigned short* bt_tg = bt + 278528;   // 2 x [512][128]
  unsigned short* bt_vh = bt + 409600;   // [128][128]
  unsigned short* bt_th = bt + 425984;   // [128][128]

  // merged weight prep (8 jobs)
  WtJobs jb;
  jb.src[0] = vpw;           jb.dst[0] = bt_vp;          jb.K[0] = 768; jb.N[0] = 128;
  jb.src[1] = tpw;           jb.dst[1] = bt_tp;          jb.K[1] = 384; jb.N[1] = 128;
  jb.src[2] = vgw;           jb.dst[2] = bt_vg;          jb.K[2] = 128; jb.N[2] = 512;
  jb.src[3] = vgw + 65536;   jb.dst[3] = bt_vg + 65536;  jb.K[3] = 128; jb.N[3] = 512;
  jb.src[4] = tgw;           jb.dst[4] = bt_tg;          jb.K[4] = 128; jb.N[4] = 512;
  jb.src[5] = tgw + 65536;   jb.dst[5] = bt_tg + 65536;  jb.K[5] = 128; jb.N[5] = 512;
  jb.src[6] = vhw;           jb.dst[6] = bt_vh;          jb.K[6] = 128; jb.N[6] = 128;
  jb.src[7] = thw;           jb.dst[7] = bt_th;          jb.K[7] = 128; jb.N[7] = 128;
  int accb = 0;
  for (int s = 0; s < 8; ++s) { accb += (jb.K[s] * jb.N[s]) / 256; jb.blk_end[s] = accb; }
  k_wt_all<<<accb, 256, 0, stream>>>(jb);

  // CSR build
  k_init_deg<<<(N_NODES + 255) / 256, 256, 0, stream>>>(deg);
  k_hist<<<(N_EDGES + 255) / 256, 256, 0, stream>>>(ei, deg);
  k_scan<<<1, 1024, 0, stream>>>(deg, row_ptr);
  k_scatter<<<(E_TOT + 255) / 256, 256, 0, stream>>>(ei, row_ptr, deg, edge_src);

  // projections (merged)
  k_proj<<<dim3(MTILES, 2), 256, 0, stream>>>(x, bt_vp, bt_tp, vpb, tpb, h_v, h_t);

  // GAT layers
  for (int L = 0; L < 2; ++L) {
    k_layer<<<dim3(MTILES, 4), 256, 0, stream>>>(h_v, bt_vg + (size_t)L * 65536,
                                                 vgas + L * 512, vgad + L * 512,
                                                 xhb, als, ald);
    k_agg<<<N_NODES, 128, 0, stream>>>(xhb, als, ald, row_ptr, edge_src, vgb + L * HID, h_v);

    k_layer<<<dim3(MTILES, 4), 256, 0, stream>>>(h_t, bt_tg + (size_t)L * 65536,
                                                 tgas + L * 512, tgad + L * 512,
                                                 xhb, als, ald);
    k_agg<<<N_NODES, 128, 0, stream>>>(xhb, als, ald, row_ptr, edge_src, tgb + L * HID, h_t);
  }

  // epilogue
  k_modal<<<N_NODES, 128, 0, stream>>>(h_v, h_t, mw, mb, out);
  k_head<<<dim3(MTILES, 2), 256, 0, stream>>>(h_v, h_t, bt_vh, bt_th, vhb, thb, out);
}